// Round 10
// baseline (165.591 us; speedup 1.0000x reference)
//
#include <hip/hip_runtime.h>
#include <math.h>
#include <stdint.h>

typedef __attribute__((ext_vector_type(8))) short bf16x8;
typedef __attribute__((ext_vector_type(4))) float f32x4;
typedef __attribute__((ext_vector_type(4))) int   i32x4;
typedef __attribute__((ext_vector_type(2))) int   i32x2;
typedef __attribute__((ext_vector_type(4))) uint  u32x4;

#define NSITES 128
#define NBULK  126
#define NPAIR  63
#define BOND   64
#define BATCH  8192

#define PAIR_B    98304                             // 4c*3tm*2ks*4jt*1024B per pair
#define WMASK_OFF ((size_t)NPAIR * PAIR_B)          // 6,193,152
#define WS_NEED   (WMASK_OFF + (size_t)BATCH * 16)

// LDS: env double-buffer (2 parities x 2 groups x 3 terms x 16b x 128B) + reduce
#define EPAR    12288
#define RED_MAX 24576
#define RED_PSI 25088
#define SMEM_SZ 25600

#define MFMA16(a,b,c) __builtin_amdgcn_mfma_f32_16x16x32_bf16(a,b,c,0,0,0)

// ============ prepass 1: pair-product matrices M = A1(va) * A2(vb), fp32,
// then 3-term trunc-bf16 split written in MFMA-A-fragment layout ============
__global__ void prep_P(const float* __restrict__ bulk, char* __restrict__ wsd) {
    __shared__ float A2[64 * 64];    // A2[k][j] = bulk[s1][k][vb][j]
    __shared__ float W1[64 * 64];    // W1[i][k] = bulk[s0][i][va][k]
    const int p  = blockIdx.x >> 2;
    const int c  = blockIdx.x & 3;
    const int va = c & 1, vb = c >> 1;
    const int s0 = 2 * p, s1 = 2 * p + 1;

    #pragma unroll
    for (int it = 0; it < 16; ++it) {
        const int idx = threadIdx.x + it * 256;
        const int r = idx >> 6, q = idx & 63;
        A2[idx] = bulk[(size_t)s1 * 8192 + r * 128 + vb * 64 + q];
        W1[idx] = bulk[(size_t)s0 * 8192 + r * 128 + va * 64 + q];
    }
    __syncthreads();

    const int j  = threadIdx.x & 63;
    const int wq = threadIdx.x >> 6;      // i-range wq*16 .. wq*16+15
    float pacc[16];
    #pragma unroll
    for (int m = 0; m < 16; ++m) pacc[m] = 0.0f;
    for (int k = 0; k < 64; ++k) {
        const float a = A2[k * 64 + j];
        const float* wr = &W1[(wq * 16) * 64 + k];
        #pragma unroll
        for (int m = 0; m < 16; ++m)
            pacc[m] = fmaf(a, wr[m * 64], pacc[m]);
    }

    // fragment write: lane l of frag (c,tm,ks,jt) holds M[i][j] with
    //   j = jt*16 + (l&15),  i = ks*32 + (l>>4)*8 + e
    const int jt = j >> 4, row = j & 15;
    const int ks = wq >> 1;
    char* pb = wsd + (size_t)p * PAIR_B;
    #pragma unroll
    for (int mh = 0; mh < 2; ++mh) {
        const int hi = (wq & 1) * 2 + mh;
        const int lane = hi * 16 + row;
        uint h[3][8];
        #pragma unroll
        for (int e = 0; e < 8; ++e) {
            const float x  = pacc[mh * 8 + e];
            const uint  u1 = __float_as_uint(x) & 0xffff0000u;
            const float r1 = x - __uint_as_float(u1);
            const uint  u2 = __float_as_uint(r1) & 0xffff0000u;
            const float r2 = r1 - __uint_as_float(u2);
            h[0][e] = u1; h[1][e] = u2;
            h[2][e] = __float_as_uint(r2) & 0xffff0000u;
        }
        #pragma unroll
        for (int tm = 0; tm < 3; ++tm) {
            i32x4 q4;
            q4.x = (int)((h[tm][0] >> 16) | (h[tm][1] & 0xffff0000u));
            q4.y = (int)((h[tm][2] >> 16) | (h[tm][3] & 0xffff0000u));
            q4.z = (int)((h[tm][4] >> 16) | (h[tm][5] & 0xffff0000u));
            q4.w = (int)((h[tm][6] >> 16) | (h[tm][7] & 0xffff0000u));
            *(i32x4*)(pb + (size_t)(((((c * 3 + tm) * 2 + ks) * 4 + jt) * 1024)
                                    + lane * 16)) = q4;
        }
    }
}

// ============ prepass 2: pack per-batch 2-bit combos (va + 2*vb) per pair ============
__global__ void prep_cmb(const int* __restrict__ cfg, uint* __restrict__ msk) {
    const int b = blockIdx.x * 256 + threadIdx.x;
    uint wd[4] = {0u, 0u, 0u, 0u};
    #pragma unroll 1
    for (int p = 0; p < NPAIR; ++p) {
        const int va = cfg[(size_t)b * NSITES + 2 * p + 1];
        const int vb = cfg[(size_t)b * NSITES + 2 * p + 2];
        wd[p >> 4] |= (uint)(va + 2 * vb) << (2 * (p & 15));
    }
    u32x4 o; o.x = wd[0]; o.y = wd[1]; o.z = wd[2]; o.w = wd[3];
    *(u32x4*)(msk + (size_t)b * 4) = o;
}

// ============ main kernel: 8 waves (4 j-tiles x 2 batch-groups), pair steps,
//              plain C++ loads + __syncthreads (verified R4 discipline) ============

#define MPROD(TW,TE) \
    acc0 = MFMA16(Af[0][TW][0], Bf[TE][0], acc0); \
    acc1 = MFMA16(Af[1][TW][0], Bf[TE][0], acc1); \
    acc2 = MFMA16(Af[2][TW][0], Bf[TE][0], acc2); \
    acc3 = MFMA16(Af[3][TW][0], Bf[TE][0], acc3); \
    acc0 = MFMA16(Af[0][TW][1], Bf[TE][1], acc0); \
    acc1 = MFMA16(Af[1][TW][1], Bf[TE][1], acc1); \
    acc2 = MFMA16(Af[2][TW][1], Bf[TE][1], acc2); \
    acc3 = MFMA16(Af[3][TW][1], Bf[TE][1], acc3);

#define PSTEP(PIDX, PAR, CW, SH, DOSC, DOMX, DOKEEP) do { \
    const int par_ = (PAR) * EPAR; \
    bf16x8 Af[4][3][2]; \
    { const char* gp_ = ws + (size_t)(PIDX) * PAIR_B; \
      _Pragma("unroll") for (int c = 0; c < 4; ++c) \
      _Pragma("unroll") for (int tm = 0; tm < 3; ++tm) \
      _Pragma("unroll") for (int ks = 0; ks < 2; ++ks) \
          Af[c][tm][ks] = *(const bf16x8*)(gp_ + aG[c][tm][ks]); } \
    bf16x8 Bf[3][2]; \
    _Pragma("unroll") \
    for (int tm = 0; tm < 3; ++tm) { \
        Bf[tm][0] = *(const bf16x8*)(smem + par_ + aB0 + tm * 2048); \
        Bf[tm][1] = *(const bf16x8*)(smem + par_ + aB1 + tm * 2048); \
    } \
    f32x4 acc0 = {0.f,0.f,0.f,0.f}, acc1 = {0.f,0.f,0.f,0.f}; \
    f32x4 acc2 = {0.f,0.f,0.f,0.f}, acc3 = {0.f,0.f,0.f,0.f}; \
    MPROD(0,0) MPROD(0,1) MPROD(1,0) MPROD(0,2) MPROD(1,1) MPROD(2,0) \
    const uint c_ = ((CW) >> (2 * (SH))) & 3u; \
    f32x4 selA = (c_ & 1u) ? acc1 : acc0; \
    f32x4 selB = (c_ & 1u) ? acc3 : acc2; \
    f32x4 sel  = (c_ & 2u) ? selB : selA; \
    if (DOSC) { \
        f32x4 m4_ = *(const f32x4*)(smem + RED_MAX + g * 256 + lb * 16); \
        const float mm_ = fmaxf(fmaxf(fmaxf(m4_.x, m4_.y), fmaxf(m4_.z, m4_.w)), 1e-30f); \
        const int ee_ = (__float_as_int(mm_) >> 23) & 255; \
        const float sc_ = __int_as_float((254 - ee_) << 23); \
        ls += (float)(ee_ - 127) * 0.6931471805599453f; \
        sel.x *= sc_; sel.y *= sc_; sel.z *= sc_; sel.w *= sc_; \
    } \
    if (DOMX) { \
        float mx_ = fmaxf(fmaxf(fabsf(sel.x), fabsf(sel.y)), fmaxf(fabsf(sel.z), fabsf(sel.w))); \
        mx_ = fmaxf(mx_, __shfl_xor(mx_, 16)); \
        mx_ = fmaxf(mx_, __shfl_xor(mx_, 32)); \
        if (lg == 0) *(float*)(smem + RED_MAX + g * 256 + lb * 16 + jt * 4) = mx_; \
    } \
    if (DOKEEP) egf = sel; \
    uint q1[4], q2[4], q3[4]; \
    _Pragma("unroll") \
    for (int r = 0; r < 4; ++r) { \
        const float x_ = sel[r]; \
        const uint  u1_ = __float_as_uint(x_) & 0xffff0000u; \
        const float r1_ = x_ - __uint_as_float(u1_); \
        const uint  u2_ = __float_as_uint(r1_) & 0xffff0000u; \
        const float r2_ = r1_ - __uint_as_float(u2_); \
        q1[r] = u1_; q2[r] = u2_; \
        q3[r] = __float_as_uint(r2_) & 0xffff0000u; \
    } \
    const int npw_ = ((PAR) ^ 1) * EPAR; \
    { i32x2 d_; d_.x = (int)((q1[0] >> 16) | (q1[1] & 0xffff0000u)); \
      d_.y = (int)((q1[2] >> 16) | (q1[3] & 0xffff0000u)); \
      *(i32x2*)(smem + npw_ + aW) = d_; } \
    { i32x2 d_; d_.x = (int)((q2[0] >> 16) | (q2[1] & 0xffff0000u)); \
      d_.y = (int)((q2[2] >> 16) | (q2[3] & 0xffff0000u)); \
      *(i32x2*)(smem + npw_ + aW + 2048) = d_; } \
    { i32x2 d_; d_.x = (int)((q3[0] >> 16) | (q3[1] & 0xffff0000u)); \
      d_.y = (int)((q3[2] >> 16) | (q3[3] & 0xffff0000u)); \
      *(i32x2*)(smem + npw_ + aW + 4096) = d_; } \
    __syncthreads(); \
} while (0)

#define RUN_CHUNK(CB, CW, CNT, CSC, CMX, CKP) { \
    _Pragma("unroll 1") \
    for (int i = 0; i < (CNT); ++i) { \
        PSTEP((CB) * 16 + i, (i & 1), CW, i, \
              ((CSC) && i == 0), ((CMX) && i == (CNT) - 1), ((CKP) && i == (CNT) - 1)); \
    } \
}

__global__ __launch_bounds__(512, 1) void mps_main(
    const int*   __restrict__ cfg,
    const float* __restrict__ left,
    const float* __restrict__ right,
    const char*  __restrict__ ws,
    float*       __restrict__ out)
{
    __shared__ __align__(16) char smem[SMEM_SZ];
    const int t  = threadIdx.x;
    const int w  = t >> 6, l = t & 63;
    const int jt = w & 3, g = w >> 2;       // j-tile, batch-group
    const int lg = l >> 4, lb = l & 15;
    const int b  = blockIdx.x * 32 + g * 16 + lb;

    // A-fragment offsets within a pair image
    int aG[4][3][2];
    #pragma unroll
    for (int c = 0; c < 4; ++c)
        #pragma unroll
        for (int tm = 0; tm < 3; ++tm)
            #pragma unroll
            for (int ks = 0; ks < 2; ++ks)
                aG[c][tm][ks] = (((c * 3 + tm) * 2 + ks) * 4 + jt) * 1024 + l * 16;

    // env LDS offsets (group-based, XOR-swizzled) — verified R4 mapping
    const int key = lb & 7;
    const int gb  = g * 6144;
    const int aB0 = gb + lb * 128 + ((lg ^ key) * 16);
    const int aB1 = gb + lb * 128 + (((4 + lg) ^ key) * 16);
    const int aW  = gb + lb * 128 + (((jt * 2 + (lg >> 1)) ^ key) * 16) + (lg & 1) * 8;

    float ls = 0.0f;
    f32x4 egf = {0.f, 0.f, 0.f, 0.f};

    const uint* mp = (const uint*)(ws + WMASK_OFF);
    const u32x4 cmb = *(const u32x4*)(mp + (size_t)b * 4);

    // initial env from left tensor -> parity-0 env buffer
    const int jout = jt * 16 + lg * 4;
    {
        const int c0 = cfg[(size_t)b * NSITES];
        uint q1[4], q2[4], q3[4];
        #pragma unroll
        for (int r = 0; r < 4; ++r) {
            const float x  = left[c0 * BOND + jout + r];
            const uint  u1 = __float_as_uint(x) & 0xffff0000u;
            const float r1 = x - __uint_as_float(u1);
            const uint  u2 = __float_as_uint(r1) & 0xffff0000u;
            const float r2 = r1 - __uint_as_float(u2);
            q1[r] = u1; q2[r] = u2;
            q3[r] = __float_as_uint(r2) & 0xffff0000u;
        }
        i32x2 d;
        d.x = (int)((q1[0] >> 16) | (q1[1] & 0xffff0000u));
        d.y = (int)((q1[2] >> 16) | (q1[3] & 0xffff0000u));
        *(i32x2*)(smem + aW) = d;
        d.x = (int)((q2[0] >> 16) | (q2[1] & 0xffff0000u));
        d.y = (int)((q2[2] >> 16) | (q2[3] & 0xffff0000u));
        *(i32x2*)(smem + aW + 2048) = d;
        d.x = (int)((q3[0] >> 16) | (q3[1] & 0xffff0000u));
        d.y = (int)((q3[2] >> 16) | (q3[3] & 0xffff0000u));
        *(i32x2*)(smem + aW + 4096) = d;
    }
    __syncthreads();

    RUN_CHUNK(0, cmb.x, 16, false, true,  false)
    RUN_CHUNK(1, cmb.y, 16, true,  true,  false)
    RUN_CHUNK(2, cmb.z, 16, true,  true,  false)
    RUN_CHUNK(3, cmb.w, 15, true,  false, true)

    // ---- final contraction with right tensor ----
    {
        const int vl = cfg[(size_t)b * NSITES + 127];
        float ps = egf.x * right[(jout + 0) * 2 + vl]
                 + egf.y * right[(jout + 1) * 2 + vl]
                 + egf.z * right[(jout + 2) * 2 + vl]
                 + egf.w * right[(jout + 3) * 2 + vl];
        ps += __shfl_xor(ps, 16);
        ps += __shfl_xor(ps, 32);
        if (lg == 0) *(float*)(smem + RED_PSI + g * 256 + lb * 16 + jt * 4) = ps;
    }
    __syncthreads();
    if (jt == 0 && lg == 0) {
        f32x4 q = *(const f32x4*)(smem + RED_PSI + g * 256 + lb * 16);
        const float s = (q.x + q.y) + (q.z + q.w);
        out[b] = 2.0f * (ls + logf(fmaxf(fabsf(s), 1e-30f)));
    }
}

// ================= fallback fp32 kernel (R0, known-good) =================
#define WPB     16
#define TPB     (WPB * 64)
#define SITE_ELTS (BOND * 2 * BOND)

__global__ __launch_bounds__(TPB, 2) void mps_logamp_fp32(
    const int*   __restrict__ cfg, const float* __restrict__ left,
    const float* __restrict__ bulk, const float* __restrict__ right,
    float* __restrict__ out)
{
    __shared__ float Abuf[2][SITE_ELTS];
    __shared__ float envs[WPB][BOND];
    __shared__ int   cfgs[WPB * NSITES];
    const int t = threadIdx.x;
    const int w = t >> 6, l = t & 63;
    const int bbase = blockIdx.x * WPB;
    const int b = bbase + w;
    cfgs[t] = cfg[bbase * NSITES + t];
    cfgs[t + TPB] = cfg[bbase * NSITES + t + TPB];
    { const float4* src = (const float4*)bulk; float4* dst = (float4*)(&Abuf[0][0]);
      dst[t] = src[t]; dst[t + TPB] = src[t + TPB]; }
    __syncthreads();
    const int c0 = cfgs[w * NSITES];
    float e = left[c0 * BOND + l];
    float m = fabsf(e);
    #pragma unroll
    for (int k = 32; k; k >>= 1) m = fmaxf(m, __shfl_xor(m, k));
    m = fmaxf(m, 1e-30f);
    e = e / m;
    float ls = logf(m);
    envs[w][l] = e;
    for (int s = 0; s < NBULK; ++s) {
        const int cur = s & 1, nxt = cur ^ 1;
        const bool pf = (s + 1 < NBULK);
        float4 p0, p1;
        if (pf) { const float4* src = (const float4*)(bulk + (size_t)(s + 1) * SITE_ELTS);
                  p0 = src[t]; p1 = src[t + TPB]; }
        const int v = cfgs[w * NSITES + (s + 1)];
        const float* Ap = &Abuf[cur][v * BOND + l];
        const float* ev = &envs[w][0];
        float acc = 0.0f;
        #pragma unroll
        for (int i = 0; i < BOND; i += 4) {
            const float4 e4 = *(const float4*)(ev + i);
            acc = fmaf(e4.x, Ap[(i + 0) * 128], acc);
            acc = fmaf(e4.y, Ap[(i + 1) * 128], acc);
            acc = fmaf(e4.z, Ap[(i + 2) * 128], acc);
            acc = fmaf(e4.w, Ap[(i + 3) * 128], acc);
        }
        float mm = fabsf(acc);
        #pragma unroll
        for (int k = 32; k; k >>= 1) mm = fmaxf(mm, __shfl_xor(mm, k));
        mm = fmaxf(mm, 1e-30f);
        acc = acc / mm;
        ls += logf(mm);
        if (pf) { float4* dst = (float4*)(&Abuf[nxt][0]); dst[t] = p0; dst[t + TPB] = p1; }
        envs[w][l] = acc;
        e = acc;
        __syncthreads();
    }
    const int vl = cfgs[w * NSITES + (NSITES - 1)];
    float p = e * right[l * 2 + vl];
    #pragma unroll
    for (int k = 32; k; k >>= 1) p += __shfl_xor(p, k);
    const float am = fmaxf(fabsf(p), 1e-30f);
    if (l == 0) out[b] = 2.0f * (ls + logf(am));
}

extern "C" void kernel_launch(void* const* d_in, const int* in_sizes, int n_in,
                              void* d_out, int out_size, void* d_ws, size_t ws_size,
                              hipStream_t stream) {
    const int*   cfg   = (const int*)d_in[0];
    const float* left  = (const float*)d_in[1];
    const float* bulk  = (const float*)d_in[2];
    const float* right = (const float*)d_in[3];
    float*       out   = (float*)d_out;

    if (ws_size >= WS_NEED) {
        hipLaunchKernelGGL(prep_P, dim3(NPAIR * 4), dim3(256), 0, stream,
                           bulk, (char*)d_ws);
        hipLaunchKernelGGL(prep_cmb, dim3(BATCH / 256), dim3(256), 0, stream,
                           cfg, (uint*)((char*)d_ws + WMASK_OFF));
        hipLaunchKernelGGL(mps_main, dim3(BATCH / 32), dim3(512), 0, stream,
                           cfg, left, right, (const char*)d_ws, out);
    } else {
        hipLaunchKernelGGL(mps_logamp_fp32, dim3(BATCH / WPB), dim3(TPB), 0, stream,
                           cfg, left, bulk, right, out);
    }
}